// Round 6
// baseline (551.746 us; speedup 1.0000x reference)
//
#include <hip/hip_runtime.h>
#include <hip/hip_cooperative_groups.h>
#include <cstdint>
#include <cstddef>

namespace cg = cooperative_groups;

#define DEV __device__ __forceinline__

static constexpr int NN  = 50000;
static constexpr int EE  = 600000;
static constexpr int ET  = 650000;   // EE + NN self loops
static constexpr int SCAN_CHUNK = 1024;                 // 256 threads x 4
static constexpr int SCAN_NB = (NN + SCAN_CHUNK - 1) / SCAN_CHUNK;   // 49

typedef __attribute__((ext_vector_type(8))) short bf16x8;   // 8 bf16 (4 VGPR)
typedef __attribute__((ext_vector_type(4))) float f32x4;    // MFMA acc
typedef __attribute__((ext_vector_type(4))) int   i32x4;

DEV float wsum(float v){
  #pragma unroll
  for (int o = 32; o > 0; o >>= 1) v += __shfl_xor(v, o, 64);
  return v;
}
DEV float wmaxr(float v){
  #pragma unroll
  for (int o = 32; o > 0; o >>= 1) v = fmaxf(v, __shfl_xor(v, o, 64));
  return v;
}
DEV float lrelu(float x){ return x > 0.f ? x : 0.2f * x; }
DEV float eluf(float x){ return x > 0.f ? x : expm1f(x); }
DEV float ln64(float v, const float* g, const float* b, int lane){
  float mu  = wsum(v) * (1.f/64.f);
  float d   = v - mu;
  float var = wsum(d*d) * (1.f/64.f);
  return d * rsqrtf(var + 1e-5f) * g[lane] + b[lane];
}
// f32 -> bf16 (RNE) as raw ushort bits
DEV unsigned int bf16u(float f){
  unsigned int u = __float_as_uint(f);
  return (u + 0x7fffu + ((u >> 16) & 1u)) >> 16;
}
DEV float bfl(unsigned int lo16){ return __uint_as_float(lo16 << 16); }

// ---------------- cooperative preprocessing: zero + packs + degree + scan + fill ----------------
__global__ __launch_bounds__(256) void prep_kernel(const int* __restrict__ ei,
                                                   const float* __restrict__ W1,
                                                   const float* __restrict__ W2,
                                                   int* __restrict__ deg,
                                                   int* __restrict__ off,
                                                   int* __restrict__ cur,
                                                   int* __restrict__ bsum,
                                                   int* __restrict__ csr_src,
                                                   int* __restrict__ csr_eid,
                                                   short* __restrict__ Wp1,
                                                   short* __restrict__ Wp2){
  cg::grid_group grid = cg::this_grid();
  const int tid = blockIdx.x * 256 + threadIdx.x;   // 65536 threads
  __shared__ int wtot[4];

  // ---- phase A: zero deg, pack W1/W2 into MFMA A-frag layout ----
  for (int i = tid; i <= NN; i += 65536) deg[i] = 0;
  if (tid < 4096){               // W1: K=128 (ksteps=4), N=256
    int lane = tid & 63, ks = (tid >> 6) & 3, mb = tid >> 8;
    int col  = mb * 16 + (lane & 15);
    int krow = ks * 32 + (lane >> 4) * 8;
    #pragma unroll
    for (int j = 0; j < 8; j++)
      Wp1[(size_t)tid * 8 + j] = (short)bf16u(W1[(size_t)(krow + j) * 256 + col]);
  } else if (tid < 4096 + 2048){ // W2: K=256 (ksteps=8), N=64
    int t2 = tid - 4096;
    int lane = t2 & 63, ks = (t2 >> 6) & 7, mb = t2 >> 9;
    int col  = mb * 16 + (lane & 15);
    int krow = ks * 32 + (lane >> 4) * 8;
    #pragma unroll
    for (int j = 0; j < 8; j++)
      Wp2[(size_t)t2 * 8 + j] = (short)bf16u(W2[(size_t)(krow + j) * 64 + col]);
  }
  grid.sync();

  // ---- phase B: degree count ----
  for (int e = tid; e < ET; e += 65536){
    int dst = (e < EE) ? ei[EE + e] : (e - EE);
    atomicAdd(&deg[dst], 1);
  }
  grid.sync();

  // ---- phase C: per-chunk exclusive scan + block sums ----
  if (blockIdx.x < SCAN_NB){
    int t = threadIdx.x, lane = t & 63, w = t >> 6;
    int i0 = blockIdx.x * SCAN_CHUNK + t * 4;
    int v[4], s = 0;
    #pragma unroll
    for (int p = 0; p < 4; p++){ int i = i0 + p; v[p] = (i < NN) ? deg[i] : 0; s += v[p]; }
    int sc = s;
    #pragma unroll
    for (int d = 1; d < 64; d <<= 1){ int u = __shfl_up(sc, d, 64); if (lane >= d) sc += u; }
    if (lane == 63) wtot[w] = sc;
    __syncthreads();
    int woff = 0;
    #pragma unroll
    for (int k = 0; k < 4; k++) if (k < w) woff += wtot[k];
    int excl = woff + sc - s;
    #pragma unroll
    for (int p = 0; p < 4; p++){
      int i = i0 + p;
      if (i < NN) off[i] = excl;
      excl += v[p];
    }
    if (t == 0) bsum[blockIdx.x] = wtot[0] + wtot[1] + wtot[2] + wtot[3];
  }
  grid.sync();

  // ---- phase D: top scan of block sums (one wave) ----
  if (blockIdx.x == 0 && threadIdx.x < 64){
    int lane = threadIdx.x;
    int v = (lane < SCAN_NB) ? bsum[lane] : 0;
    int sc = v;
    #pragma unroll
    for (int d = 1; d < 64; d <<= 1){ int u = __shfl_up(sc, d, 64); if (lane >= d) sc += u; }
    if (lane < SCAN_NB) bsum[lane] = sc - v;
    if (lane == 63) bsum[SCAN_NB] = sc;
  }
  grid.sync();

  // ---- phase E: add block offsets ----
  if (blockIdx.x < SCAN_NB){
    int i0 = blockIdx.x * SCAN_CHUNK + threadIdx.x * 4;
    int add = bsum[blockIdx.x];
    #pragma unroll
    for (int p = 0; p < 4; p++){
      int j = i0 + p;
      if (j < NN){ int u = off[j] + add; off[j] = u; cur[j] = u; }
    }
    if (blockIdx.x == 0 && threadIdx.x == 0) off[NN] = bsum[SCAN_NB];
  }
  grid.sync();

  // ---- phase F: fill CSR ----
  for (int e = tid; e < ET; e += 65536){
    int src, dst;
    if (e < EE){ src = ei[e]; dst = ei[EE + e]; } else { src = dst = e - EE; }
    int pos = atomicAdd(&cur[dst], 1);
    csr_src[pos] = src;
    csr_eid[pos] = e;
  }
}

// ---------------- MFMA GEMM (LDS-free) + bf16 C-store + fused att dots ----------------
template<int KSTEPS, int MBLKS, int NH, bool INF32>
__global__ __launch_bounds__(256) void mfma_gemm_att(const short* __restrict__ Wp,
                                                     const float* __restrict__ Xf,
                                                     const unsigned short* __restrict__ Xh,
                                                     unsigned short* __restrict__ Cb,
                                                     const float* __restrict__ asrc,
                                                     const float* __restrict__ adst,
                                                     float* __restrict__ es,
                                                     float* __restrict__ ed, int M){
  constexpr int K = KSTEPS * 32, N = MBLKS * 16;
  int lane  = threadIdx.x & 63;
  int wv    = threadIdx.x >> 6;
  int quad  = lane >> 4;
  int node  = blockIdx.x * 64 + wv * 16 + (lane & 15);
  bool nv   = node < M;
  int nodec = nv ? node : M - 1;

  f32x4 acc[MBLKS];
  #pragma unroll
  for (int m = 0; m < MBLKS; m++) acc[m] = (f32x4){0.f, 0.f, 0.f, 0.f};

  #pragma unroll
  for (int ks = 0; ks < KSTEPS; ks++){
    int k0 = ks * 32 + quad * 8;
    bf16x8 bfrag;
    if (INF32){
      float4 u = *(const float4*)(Xf + (size_t)nodec * K + k0);
      float4 v = *(const float4*)(Xf + (size_t)nodec * K + k0 + 4);
      i32x4 bi;
      bi.x = (int)(bf16u(u.x) | (bf16u(u.y) << 16));
      bi.y = (int)(bf16u(u.z) | (bf16u(u.w) << 16));
      bi.z = (int)(bf16u(v.x) | (bf16u(v.y) << 16));
      bi.w = (int)(bf16u(v.z) | (bf16u(v.w) << 16));
      bfrag = __builtin_bit_cast(bf16x8, bi);
    } else {
      bfrag = *(const bf16x8*)(Xh + (size_t)nodec * K + k0);
    }
    #pragma unroll
    for (int mb = 0; mb < MBLKS; mb++){
      bf16x8 afrag = *(const bf16x8*)(Wp + ((size_t)(mb * KSTEPS + ks) * 64 + lane) * 8);
      acc[mb] = __builtin_amdgcn_mfma_f32_16x16x32_bf16(afrag, bfrag, acc[mb], 0, 0, 0);
    }
  }

  if (nv){
    unsigned short* crow = Cb + (size_t)node * N;
    #pragma unroll
    for (int mb = 0; mb < MBLKS; mb++){
      uint2 p;
      p.x = bf16u(acc[mb][0]) | (bf16u(acc[mb][1]) << 16);
      p.y = bf16u(acc[mb][2]) | (bf16u(acc[mb][3]) << 16);
      *(uint2*)(crow + mb * 16 + quad * 4) = p;
    }
  }

  float ps[NH], pd[NH];
  #pragma unroll
  for (int h = 0; h < NH; h++){ ps[h] = 0.f; pd[h] = 0.f; }
  #pragma unroll
  for (int mb = 0; mb < MBLKS; mb++){
    int h = (NH == 1) ? 0 : (mb >> 2);
    #pragma unroll
    for (int r = 0; r < 4; r++){
      int c = mb * 16 + quad * 4 + r;
      ps[h] = fmaf(acc[mb][r], asrc[c], ps[h]);
      pd[h] = fmaf(acc[mb][r], adst[c], pd[h]);
    }
  }
  #pragma unroll
  for (int h = 0; h < NH; h++){
    ps[h] += __shfl_xor(ps[h], 16, 64); ps[h] += __shfl_xor(ps[h], 32, 64);
    pd[h] += __shfl_xor(pd[h], 16, 64); pd[h] += __shfl_xor(pd[h], 32, 64);
  }
  if (quad == 0 && nv){
    if (NH == 4){
      *(float4*)(es + (size_t)node * 4) = make_float4(ps[0], ps[1], ps[2], ps[3]);
      *(float4*)(ed + (size_t)node * 4) = make_float4(pd[0], pd[1], pd[2], pd[3]);
    } else {
      es[node] = ps[0];
      ed[node] = pd[0];
    }
  }
}

// ---------------- layer-1 aggregation (bf16 H1 gather, bf16 h1 out) ----------------
DEV void acc4u(uint2 g, float q, float& ax, float& ay, float& az, float& aw){
  ax = fmaf(__uint_as_float(g.x << 16),         q, ax);
  ay = fmaf(__uint_as_float(g.x & 0xffff0000u), q, ay);
  az = fmaf(__uint_as_float(g.y << 16),         q, az);
  aw = fmaf(__uint_as_float(g.y & 0xffff0000u), q, aw);
}

__global__ __launch_bounds__(256) void agg1_kernel(const int* __restrict__ off,
                                                   const int* __restrict__ csr_src,
                                                   const unsigned short* __restrict__ H1b,
                                                   const float* __restrict__ es,
                                                   const float* __restrict__ ed,
                                                   const float* __restrict__ b1,
                                                   const float* __restrict__ lng,
                                                   const float* __restrict__ lnb,
                                                   unsigned short* __restrict__ h1b, int n){
  __shared__ float wshT[4][4][68];   // [wave][head][edge], padded
  __shared__ int   ssh[4][64];
  int wv   = threadIdx.x >> 6;
  int wid  = (blockIdx.x * blockDim.x + threadIdx.x) >> 6;
  int lane = threadIdx.x & 63;
  if (wid >= n) return;
  int s0  = off[wid];
  int deg = off[wid + 1] - s0;
  const float4 edv = *(const float4*)(ed + (size_t)wid * 4);

  float v0, v1, v2, v3;

  if (deg <= 64){
    bool vld = lane < deg;
    int srcl = vld ? csr_src[s0 + lane] : 0;
    float4 e4 = vld ? *(const float4*)(es + (size_t)srcl * 4)
                    : make_float4(-1e30f, -1e30f, -1e30f, -1e30f);
    float e0 = vld ? lrelu(e4.x + edv.x) : -1e30f;
    float e1 = vld ? lrelu(e4.y + edv.y) : -1e30f;
    float e2 = vld ? lrelu(e4.z + edv.z) : -1e30f;
    float e3 = vld ? lrelu(e4.w + edv.w) : -1e30f;
    float m0 = wmaxr(e0), m1 = wmaxr(e1), m2 = wmaxr(e2), m3 = wmaxr(e3);
    float w0 = vld ? __expf(e0 - m0) : 0.f;
    float w1 = vld ? __expf(e1 - m1) : 0.f;
    float w2 = vld ? __expf(e2 - m2) : 0.f;
    float w3 = vld ? __expf(e3 - m3) : 0.f;
    w0 /= (wsum(w0) + 1e-16f);
    w1 /= (wsum(w1) + 1e-16f);
    w2 /= (wsum(w2) + 1e-16f);
    w3 /= (wsum(w3) + 1e-16f);
    ssh[wv][lane] = srcl;
    wshT[wv][0][lane] = w0; wshT[wv][1][lane] = w1;
    wshT[wv][2][lane] = w2; wshT[wv][3][lane] = w3;
    __builtin_amdgcn_wave_barrier();   // same-wave DS in-order; pin compiler order

    int h = lane >> 4;
    const float* wrow = &wshT[wv][h][0];
    int lane4 = lane * 4;
    float ax = 0.f, ay = 0.f, az = 0.f, aw = 0.f;
    int t = 0;
    for (; t + 8 <= deg; t += 8){
      i32x4 sA = *(const i32x4*)&ssh[wv][t];
      i32x4 sB = *(const i32x4*)&ssh[wv][t + 4];
      f32x4 qA = *(const f32x4*)&wrow[t];
      f32x4 qB = *(const f32x4*)&wrow[t + 4];
      uint2 g0 = *(const uint2*)(H1b + (size_t)sA.x * 256 + lane4);
      uint2 g1 = *(const uint2*)(H1b + (size_t)sA.y * 256 + lane4);
      uint2 g2 = *(const uint2*)(H1b + (size_t)sA.z * 256 + lane4);
      uint2 g3 = *(const uint2*)(H1b + (size_t)sA.w * 256 + lane4);
      uint2 g4 = *(const uint2*)(H1b + (size_t)sB.x * 256 + lane4);
      uint2 g5 = *(const uint2*)(H1b + (size_t)sB.y * 256 + lane4);
      uint2 g6 = *(const uint2*)(H1b + (size_t)sB.z * 256 + lane4);
      uint2 g7 = *(const uint2*)(H1b + (size_t)sB.w * 256 + lane4);
      acc4u(g0, qA.x, ax, ay, az, aw);
      acc4u(g1, qA.y, ax, ay, az, aw);
      acc4u(g2, qA.z, ax, ay, az, aw);
      acc4u(g3, qA.w, ax, ay, az, aw);
      acc4u(g4, qB.x, ax, ay, az, aw);
      acc4u(g5, qB.y, ax, ay, az, aw);
      acc4u(g6, qB.z, ax, ay, az, aw);
      acc4u(g7, qB.w, ax, ay, az, aw);
    }
    for (; t < deg; t++){
      int a0 = ssh[wv][t];
      float q0 = wrow[t];
      uint2 g0 = *(const uint2*)(H1b + (size_t)a0 * 256 + lane4);
      acc4u(g0, q0, ax, ay, az, aw);
    }
    float4 bb = *(const float4*)(b1 + lane4);
    v0 = eluf(ax + bb.x); v1 = eluf(ay + bb.y);
    v2 = eluf(az + bb.z); v3 = eluf(aw + bb.w);
    float mu = wsum(v0 + v1 + v2 + v3) * (1.f/256.f);
    float q  = (v0-mu)*(v0-mu) + (v1-mu)*(v1-mu) + (v2-mu)*(v2-mu) + (v3-mu)*(v3-mu);
    float rstd = rsqrtf(wsum(q) * (1.f/256.f) + 1e-5f);
    float4 g4v = *(const float4*)(lng + lane4);
    float4 bo  = *(const float4*)(lnb + lane4);
    uint2 p;
    p.x = bf16u((v0-mu)*rstd*g4v.x + bo.x) | (bf16u((v1-mu)*rstd*g4v.y + bo.y) << 16);
    p.y = bf16u((v2-mu)*rstd*g4v.z + bo.z) | (bf16u((v3-mu)*rstd*g4v.w + bo.w) << 16);
    *(uint2*)(h1b + (size_t)wid * 256 + lane4) = p;
    return;
  }

  // slow path: deg > 64 (rare); lane = channel within head
  float m0 = -1e30f, m1 = -1e30f, m2 = -1e30f, m3 = -1e30f;
  for (int j = lane; j < deg; j += 64){
    int src = csr_src[s0 + j];
    float4 e4 = *(const float4*)(es + (size_t)src * 4);
    m0 = fmaxf(m0, lrelu(e4.x + edv.x));
    m1 = fmaxf(m1, lrelu(e4.y + edv.y));
    m2 = fmaxf(m2, lrelu(e4.z + edv.z));
    m3 = fmaxf(m3, lrelu(e4.w + edv.w));
  }
  m0 = wmaxr(m0); m1 = wmaxr(m1); m2 = wmaxr(m2); m3 = wmaxr(m3);
  float acc0 = 0.f, acc1 = 0.f, acc2 = 0.f, acc3 = 0.f;
  float den0 = 0.f, den1 = 0.f, den2 = 0.f, den3 = 0.f;
  for (int j = 0; j < deg; j++){
    int src = csr_src[s0 + j];
    float4 e4 = *(const float4*)(es + (size_t)src * 4);
    float x0 = __expf(lrelu(e4.x + edv.x) - m0);
    float x1 = __expf(lrelu(e4.y + edv.y) - m1);
    float x2 = __expf(lrelu(e4.z + edv.z) - m2);
    float x3 = __expf(lrelu(e4.w + edv.w) - m3);
    den0 += x0; den1 += x1; den2 += x2; den3 += x3;
    const unsigned short* hp = H1b + (size_t)src * 256;
    acc0 = fmaf(bfl(hp[lane]),       x0, acc0);
    acc1 = fmaf(bfl(hp[64 + lane]),  x1, acc1);
    acc2 = fmaf(bfl(hp[128 + lane]), x2, acc2);
    acc3 = fmaf(bfl(hp[192 + lane]), x3, acc3);
  }
  v0 = eluf(acc0 / (den0 + 1e-16f) + b1[lane]);
  v1 = eluf(acc1 / (den1 + 1e-16f) + b1[64 + lane]);
  v2 = eluf(acc2 / (den2 + 1e-16f) + b1[128 + lane]);
  v3 = eluf(acc3 / (den3 + 1e-16f) + b1[192 + lane]);
  float mu = wsum(v0 + v1 + v2 + v3) * (1.f/256.f);
  float q  = (v0-mu)*(v0-mu) + (v1-mu)*(v1-mu) + (v2-mu)*(v2-mu) + (v3-mu)*(v3-mu);
  float rstd = rsqrtf(wsum(q) * (1.f/256.f) + 1e-5f);
  unsigned short* o = h1b + (size_t)wid * 256;
  o[lane]       = (unsigned short)bf16u((v0-mu)*rstd*lng[lane]       + lnb[lane]);
  o[64 + lane]  = (unsigned short)bf16u((v1-mu)*rstd*lng[64 + lane]  + lnb[64 + lane]);
  o[128 + lane] = (unsigned short)bf16u((v2-mu)*rstd*lng[128 + lane] + lnb[128 + lane]);
  o[192 + lane] = (unsigned short)bf16u((v3-mu)*rstd*lng[192 + lane] + lnb[192 + lane]);
}

// ---------------- layer-2 aggregation (1 head) + fused dueling head ----------------
// Pair layout: lane covers channels {2*sub, 2*sub+1}, sub=lane&31; halves 0/1
// process even/odd edges, combined via shfl_xor(32).
__global__ __launch_bounds__(256) void agg2_head(const int* __restrict__ off,
                                                 const int* __restrict__ csr_src,
                                                 const int* __restrict__ csr_eid,
                                                 const unsigned short* __restrict__ H2b,
                                                 const float* __restrict__ es,
                                                 const float* __restrict__ ed,
                                                 const float* __restrict__ b2,
                                                 const float* __restrict__ lng,
                                                 const float* __restrict__ lnb,
                                                 const float* __restrict__ semb,
                                                 const int* __restrict__ active,
                                                 const int* __restrict__ stepp,
                                                 const float* __restrict__ fc0w, const float* __restrict__ fc0b,
                                                 const float* __restrict__ fc1w, const float* __restrict__ fc1b,
                                                 const float* __restrict__ fc2w, const float* __restrict__ fc2b,
                                                 const float* __restrict__ fc3w, const float* __restrict__ fc3b,
                                                 const float* __restrict__ valw, const float* __restrict__ valb,
                                                 const float* __restrict__ advw, const float* __restrict__ advb,
                                                 const float* __restrict__ lnhg, const float* __restrict__ lnhb,
                                                 const float* __restrict__ lnfg, const float* __restrict__ lnfb,
                                                 float* __restrict__ h2out,
                                                 float* __restrict__ alpha_out,
                                                 float* __restrict__ logits, int n){
  __shared__ float wsa[4][64];
  __shared__ int   ssa[4][64];
  __shared__ float shh[192];
  int wv   = threadIdx.x >> 6;
  int wid  = (blockIdx.x * blockDim.x + threadIdx.x) >> 6;
  int lane = threadIdx.x & 63;
  if (wid >= n) return;
  int s0  = off[wid];
  int deg = off[wid + 1] - s0;
  float edv = ed[wid];
  int sub = lane & 31, half = lane >> 5;
  const unsigned short* base = H2b + sub * 2;
  float va, vb;

  if (deg <= 64){
    bool vld = lane < deg;
    int srcl = vld ? csr_src[s0 + lane] : 0;
    float el = vld ? lrelu(es[srcl] + edv) : -1e30f;
    float m  = wmaxr(el);
    float w  = vld ? __expf(el - m) : 0.f;
    float den = wsum(w) + 1e-16f;
    float wl = w / den;
    if (vld) alpha_out[csr_eid[s0 + lane]] = wl;
    ssa[wv][lane] = srcl;
    wsa[wv][lane] = vld ? wl : 0.f;
    __builtin_amdgcn_wave_barrier();

    float a0 = 0.f, a1 = 0.f;
    int nsteps = (deg + 1) >> 1;
    int j = 0;
    for (; j + 4 <= nsteps; j += 4){
      int e0 = 2 * j + half;
      int sA = ssa[wv][e0],     sB = ssa[wv][e0 + 2];
      int sC = ssa[wv][e0 + 4], sD = ssa[wv][e0 + 6];
      float wA = wsa[wv][e0],     wB = wsa[wv][e0 + 2];
      float wC = wsa[wv][e0 + 4], wD = wsa[wv][e0 + 6];
      unsigned int gA = *(const unsigned int*)(base + (size_t)sA * 64);
      unsigned int gB = *(const unsigned int*)(base + (size_t)sB * 64);
      unsigned int gC = *(const unsigned int*)(base + (size_t)sC * 64);
      unsigned int gD = *(const unsigned int*)(base + (size_t)sD * 64);
      a0 = fmaf(__uint_as_float(gA << 16),         wA, a0);
      a1 = fmaf(__uint_as_float(gA & 0xffff0000u), wA, a1);
      a0 = fmaf(__uint_as_float(gB << 16),         wB, a0);
      a1 = fmaf(__uint_as_float(gB & 0xffff0000u), wB, a1);
      a0 = fmaf(__uint_as_float(gC << 16),         wC, a0);
      a1 = fmaf(__uint_as_float(gC & 0xffff0000u), wC, a1);
      a0 = fmaf(__uint_as_float(gD << 16),         wD, a0);
      a1 = fmaf(__uint_as_float(gD & 0xffff0000u), wD, a1);
    }
    for (; j < nsteps; j++){
      int e = 2 * j + half;
      int sA = ssa[wv][e];
      float wA = wsa[wv][e];
      unsigned int g = *(const unsigned int*)(base + (size_t)sA * 64);
      a0 = fmaf(__uint_as_float(g << 16),         wA, a0);
      a1 = fmaf(__uint_as_float(g & 0xffff0000u), wA, a1);
    }
    a0 += __shfl_xor(a0, 32, 64);
    a1 += __shfl_xor(a1, 32, 64);
    va = a0 + b2[2 * sub];
    vb = a1 + b2[2 * sub + 1];
  } else {
    // slow path: all lanes process all edges (halves duplicate — harmless)
    float m = -1e30f;
    for (int j2 = lane; j2 < deg; j2 += 64)
      m = fmaxf(m, lrelu(es[csr_src[s0 + j2]] + edv));
    m = wmaxr(m);
    float den = 0.f;
    for (int j2 = lane; j2 < deg; j2 += 64)
      den += __expf(lrelu(es[csr_src[s0 + j2]] + edv) - m);
    den = wsum(den) + 1e-16f;
    float a0 = 0.f, a1 = 0.f;
    for (int j2 = 0; j2 < deg; j2++){
      int srcj = csr_src[s0 + j2];
      float a = __expf(lrelu(es[srcj] + edv) - m) / den;
      if (lane == 0) alpha_out[csr_eid[s0 + j2]] = a;
      unsigned int g = *(const unsigned int*)(base + (size_t)srcj * 64);
      a0 = fmaf(__uint_as_float(g << 16),         a, a0);
      a1 = fmaf(__uint_as_float(g & 0xffff0000u), a, a1);
    }
    va = a0 + b2[2 * sub];
    vb = a1 + b2[2 * sub + 1];
  }

  // LN over 64 ch (each pair appears twice across lanes -> /128)
  float mu = wsum(va + vb) * (1.f/128.f);
  float d0 = va - mu, d1 = vb - mu;
  float rstd = rsqrtf(wsum(d0*d0 + d1*d1) * (1.f/128.f) + 1e-5f);
  float n0v = d0 * rstd * lng[2 * sub]     + lnb[2 * sub];
  float n1v = d1 * rstd * lng[2 * sub + 1] + lnb[2 * sub + 1];
  if (half == 0)
    *(float2*)(h2out + (size_t)wid * 64 + 2 * sub) = make_float2(n0v, n1v);

  // ---- fused dueling head: the wave owning the active node finishes the net ----
  if (wid == active[0]){
    int t = lane;
    // reconstruct h2[active][t] from pair layout
    float ra = __shfl(n0v, t >> 1, 64);
    float rb = __shfl(n1v, t >> 1, 64);
    float h2t = (t & 1) ? rb : ra;

    float sval = (float)(stepp[0] + 1) * 0.01f;
    float stepsv = ln64(fmaxf(fmaf(sval, fc0w[t], fc0b[t]), 0.f), lnhg, lnhb, t);

    float acc = fc1b[t];
    #pragma unroll 8
    for (int k = 0; k < 768; k++) acc = fmaf(semb[k], fc1w[k * 64 + t], acc);
    float sentv = ln64(fmaxf(acc, 0.f), lnhg, lnhb, t) + stepsv;
    shh[t] = sentv;
    __builtin_amdgcn_wave_barrier();
    float acc2 = fc2b[t];
    #pragma unroll 8
    for (int k = 0; k < 64; k++) acc2 = fmaf(shh[k], fc2w[k * 64 + t], acc2);
    __builtin_amdgcn_wave_barrier();
    float sent2 = ln64(fmaxf(acc2, 0.f), lnhg, lnhb, t);

    float c0 = h2t, c1 = sent2;
    float mu2 = wsum(c0 + c1) * (1.f/128.f);
    float q2  = (c0-mu2)*(c0-mu2) + (c1-mu2)*(c1-mu2);
    float rs2 = rsqrtf(wsum(q2) * (1.f/128.f) + 1e-5f);
    shh[t]      = (c0-mu2)*rs2*lnfg[t]      + lnfb[t];
    shh[64 + t] = (c1-mu2)*rs2*lnfg[64 + t] + lnfb[64 + t];
    __builtin_amdgcn_wave_barrier();

    float acc3 = fc3b[t];
    #pragma unroll 8
    for (int k = 0; k < 128; k++) acc3 = fmaf(shh[k], fc3w[k * 64 + t], acc3);
    float a2v = ln64(fmaxf(acc3, 0.f), lnhg, lnhb, t);
    shh[128 + t] = a2v;
    __builtin_amdgcn_wave_barrier();

    float val = wsum(a2v * valw[t]) + valb[0];
    float advv = 0.f;
    if (t < 32){
      advv = advb[t];
      #pragma unroll 8
      for (int k = 0; k < 64; k++) advv = fmaf(shh[128 + k], advw[k * 32 + t], advv);
    }
    float am = wsum(t < 32 ? advv : 0.f) * (1.f/32.f);
    if (t < 32) logits[t] = tanhf(val + advv - am);
  }
}

extern "C" void kernel_launch(void* const* d_in, const int* in_sizes, int n_in,
                              void* d_out, int out_size, void* d_ws, size_t ws_size,
                              hipStream_t stream) {
  const float* x     = (const float*)d_in[0];
  const int*   ei    = (const int*)  d_in[1];
  const float* semb  = (const float*)d_in[2];
  const int*   act   = (const int*)  d_in[3];
  const int*   step  = (const int*)  d_in[4];
  const float* W1    = (const float*)d_in[5];
  const float* as1   = (const float*)d_in[6];
  const float* ad1   = (const float*)d_in[7];
  const float* b1    = (const float*)d_in[8];
  const float* W2    = (const float*)d_in[9];
  const float* as2   = (const float*)d_in[10];
  const float* ad2   = (const float*)d_in[11];
  const float* b2    = (const float*)d_in[12];
  const float* fc0w  = (const float*)d_in[13];
  const float* fc0b  = (const float*)d_in[14];
  const float* fc1w  = (const float*)d_in[15];
  const float* fc1b  = (const float*)d_in[16];
  const float* fc2w  = (const float*)d_in[17];
  const float* fc2b  = (const float*)d_in[18];
  const float* fc3w  = (const float*)d_in[19];
  const float* fc3b  = (const float*)d_in[20];
  const float* valw  = (const float*)d_in[21];
  const float* valb  = (const float*)d_in[22];
  const float* advw  = (const float*)d_in[23];
  const float* advb  = (const float*)d_in[24];
  const float* lnhg  = (const float*)d_in[25];
  const float* lnhb  = (const float*)d_in[26];
  const float* lnfg  = (const float*)d_in[27];
  const float* lnfb  = (const float*)d_in[28];
  const float* lnag  = (const float*)d_in[29];
  const float* lnab  = (const float*)d_in[30];

  char* ws = (char*)d_ws;
  size_t o = 0;
  auto alloc = [&](size_t bytes) -> void* {
    o = (o + 255) & ~(size_t)255;
    void* p = ws + o;
    o += bytes;
    return p;
  };
  int*   deg     = (int*)  alloc((size_t)(NN + 1) * 4);
  int*   off     = (int*)  alloc((size_t)(NN + 1) * 4);
  int*   cur     = (int*)  alloc((size_t)NN * 4);
  int*   bsum    = (int*)  alloc((size_t)(SCAN_NB + 1) * 4);
  int*   csr_src = (int*)  alloc((size_t)ET * 4);
  int*   csr_eid = (int*)  alloc((size_t)ET * 4);
  short* Wp1     = (short*)alloc((size_t)4096 * 8 * 2);   // 64 KB
  short* Wp2     = (short*)alloc((size_t)2048 * 8 * 2);   // 32 KB
  unsigned short* H1b = (unsigned short*)alloc((size_t)NN * 256 * 2);  // bf16 H1
  unsigned short* h1b = (unsigned short*)alloc((size_t)NN * 256 * 2);  // bf16 h1 (post agg1)
  float* es1     = (float*)alloc((size_t)NN * 16);
  float* ed1     = (float*)alloc((size_t)NN * 16);
  unsigned short* H2b = H1b;   // aliases; lifetimes don't overlap
  float* es2 = es1;
  float* ed2 = ed1;

  float* logits    = (float*)d_out;
  float* h2out     = (float*)d_out + 32;
  float* alpha_out = (float*)d_out + 32 + (size_t)NN * 64;

  // ---- single cooperative dispatch: zero + packs + degree + scan + fill ----
  {
    void* args[] = { (void*)&ei, (void*)&W1, (void*)&W2,
                     (void*)&deg, (void*)&off, (void*)&cur, (void*)&bsum,
                     (void*)&csr_src, (void*)&csr_eid, (void*)&Wp1, (void*)&Wp2 };
    hipLaunchCooperativeKernel((void*)prep_kernel, dim3(256), dim3(256), args, 0, stream);
  }

  // layer 1: MFMA GEMM + fused att dots
  mfma_gemm_att<4, 16, 4, true><<<(NN + 63) / 64, 256, 0, stream>>>(
      Wp1, x, nullptr, H1b, as1, ad1, es1, ed1, NN);
  agg1_kernel<<<NN / 4, 256, 0, stream>>>(off, csr_src, H1b, es1, ed1, b1, lnag, lnab, h1b, NN);

  // layer 2
  mfma_gemm_att<8, 4, 1, false><<<(NN + 63) / 64, 256, 0, stream>>>(
      Wp2, nullptr, h1b, H2b, as2, ad2, es2, ed2, NN);
  agg2_head<<<NN / 4, 256, 0, stream>>>(off, csr_src, csr_eid, H2b, es2, ed2, b2,
                                        lnhg, lnhb,
                                        semb, act, step,
                                        fc0w, fc0b, fc1w, fc1b, fc2w, fc2b, fc3w, fc3b,
                                        valw, valb, advw, advb,
                                        lnhg, lnhb, lnfg, lnfb,
                                        h2out, alpha_out, logits, NN);
}

// Round 7
// 372.076 us; speedup vs baseline: 1.4829x; 1.4829x over previous
//
#include <hip/hip_runtime.h>
#include <cstdint>
#include <cstddef>

#define DEV __device__ __forceinline__

static constexpr int NN  = 50000;
static constexpr int EE  = 600000;
static constexpr int ET  = 650000;   // EE + NN self loops
static constexpr int SCAN_CHUNK = 1024;                 // 256 threads x 4
static constexpr int SCAN_NB = (NN + SCAN_CHUNK - 1) / SCAN_CHUNK;   // 49

typedef __attribute__((ext_vector_type(8))) short bf16x8;   // 8 bf16 (4 VGPR)
typedef __attribute__((ext_vector_type(4))) float f32x4;    // MFMA acc
typedef __attribute__((ext_vector_type(4))) int   i32x4;

DEV float wsum(float v){
  #pragma unroll
  for (int o = 32; o > 0; o >>= 1) v += __shfl_xor(v, o, 64);
  return v;
}
DEV float wmaxr(float v){
  #pragma unroll
  for (int o = 32; o > 0; o >>= 1) v = fmaxf(v, __shfl_xor(v, o, 64));
  return v;
}
DEV float lrelu(float x){ return x > 0.f ? x : 0.2f * x; }
DEV float eluf(float x){ return x > 0.f ? x : expm1f(x); }
DEV float ln64(float v, const float* g, const float* b, int lane){
  float mu  = wsum(v) * (1.f/64.f);
  float d   = v - mu;
  float var = wsum(d*d) * (1.f/64.f);
  return d * rsqrtf(var + 1e-5f) * g[lane] + b[lane];
}
// f32 -> bf16 (RNE) as raw ushort bits
DEV unsigned int bf16u(float f){
  unsigned int u = __float_as_uint(f);
  return (u + 0x7fffu + ((u >> 16) & 1u)) >> 16;
}
DEV float bfl(unsigned int lo16){ return __uint_as_float(lo16 << 16); }

// ---------------- CSR build (full-occupancy separate kernels) ----------------
__global__ void degree_kernel(const int* __restrict__ ei, int* __restrict__ deg){
  int e = blockIdx.x * blockDim.x + threadIdx.x;
  if (e >= ET) return;
  int dst = (e < EE) ? ei[EE + e] : (e - EE);
  atomicAdd(&deg[dst], 1);
}

__global__ __launch_bounds__(256) void scan_part(const int* __restrict__ deg,
                                                 int* __restrict__ off,
                                                 int* __restrict__ bsum, int n){
  __shared__ int wtot[4];
  int tid = threadIdx.x, lane = tid & 63, w = tid >> 6;
  int i0 = blockIdx.x * SCAN_CHUNK + tid * 4;
  int v[4], s = 0;
  #pragma unroll
  for (int p = 0; p < 4; p++){ int i = i0 + p; v[p] = (i < n) ? deg[i] : 0; s += v[p]; }
  int sc = s;
  #pragma unroll
  for (int d = 1; d < 64; d <<= 1){ int t = __shfl_up(sc, d, 64); if (lane >= d) sc += t; }
  if (lane == 63) wtot[w] = sc;
  __syncthreads();
  int woff = 0;
  #pragma unroll
  for (int k = 0; k < 4; k++) if (k < w) woff += wtot[k];
  int excl = woff + sc - s;
  #pragma unroll
  for (int p = 0; p < 4; p++){
    int i = i0 + p;
    if (i < n) off[i] = excl;
    excl += v[p];
  }
  if (tid == 0) bsum[blockIdx.x] = wtot[0] + wtot[1] + wtot[2] + wtot[3];
}

__global__ __launch_bounds__(64) void scan_top(int* __restrict__ bsum, int nb){
  int lane = threadIdx.x;
  int v = (lane < nb) ? bsum[lane] : 0;
  int sc = v;
  #pragma unroll
  for (int d = 1; d < 64; d <<= 1){ int t = __shfl_up(sc, d, 64); if (lane >= d) sc += t; }
  if (lane < nb) bsum[lane] = sc - v;
  if (lane == 63) bsum[nb] = sc;    // grand total
}

__global__ __launch_bounds__(256) void scan_add(int* __restrict__ off,
                                                int* __restrict__ cur,
                                                const int* __restrict__ bsum, int n, int nb){
  int i0 = blockIdx.x * SCAN_CHUNK + threadIdx.x * 4;
  int add = bsum[blockIdx.x];
  #pragma unroll
  for (int p = 0; p < 4; p++){
    int j = i0 + p;
    if (j < n){ int t = off[j] + add; off[j] = t; cur[j] = t; }
  }
  if (blockIdx.x == 0 && threadIdx.x == 0) off[n] = bsum[nb];
}

__global__ void fill_csr(const int* __restrict__ ei, int* __restrict__ cur,
                         int* __restrict__ csr_src, int* __restrict__ csr_eid){
  int e = blockIdx.x * blockDim.x + threadIdx.x;
  if (e >= ET) return;
  int src, dst;
  if (e < EE){ src = ei[e]; dst = ei[EE + e]; } else { src = dst = e - EE; }
  int pos = atomicAdd(&cur[dst], 1);
  csr_src[pos] = src;
  csr_eid[pos] = e;
}

// pack W1 (4096 frag-threads) and W2 (2048 frag-threads) in one dispatch
__global__ __launch_bounds__(256) void pack_both(const float* __restrict__ W1,
                                                 const float* __restrict__ W2,
                                                 short* __restrict__ Wp1,
                                                 short* __restrict__ Wp2){
  int tid = blockIdx.x * 256 + threadIdx.x;
  if (tid < 4096){               // W1: K=128 (ksteps=4), N=256
    int lane = tid & 63, ks = (tid >> 6) & 3, mb = tid >> 8;
    int col  = mb * 16 + (lane & 15);
    int krow = ks * 32 + (lane >> 4) * 8;
    #pragma unroll
    for (int j = 0; j < 8; j++)
      Wp1[(size_t)tid * 8 + j] = (short)bf16u(W1[(size_t)(krow + j) * 256 + col]);
  } else if (tid < 4096 + 2048){ // W2: K=256 (ksteps=8), N=64
    int t2 = tid - 4096;
    int lane = t2 & 63, ks = (t2 >> 6) & 7, mb = t2 >> 9;
    int col  = mb * 16 + (lane & 15);
    int krow = ks * 32 + (lane >> 4) * 8;
    #pragma unroll
    for (int j = 0; j < 8; j++)
      Wp2[(size_t)t2 * 8 + j] = (short)bf16u(W2[(size_t)(krow + j) * 64 + col]);
  }
}

// ---------------- MFMA GEMM (LDS-free) + bf16 C-store + fused att dots ----------------
template<int KSTEPS, int MBLKS, int NH, bool INF32>
__global__ __launch_bounds__(256) void mfma_gemm_att(const short* __restrict__ Wp,
                                                     const float* __restrict__ Xf,
                                                     const unsigned short* __restrict__ Xh,
                                                     unsigned short* __restrict__ Cb,
                                                     const float* __restrict__ asrc,
                                                     const float* __restrict__ adst,
                                                     float* __restrict__ es,
                                                     float* __restrict__ ed, int M){
  constexpr int K = KSTEPS * 32, N = MBLKS * 16;
  int lane  = threadIdx.x & 63;
  int wv    = threadIdx.x >> 6;
  int quad  = lane >> 4;
  int node  = blockIdx.x * 64 + wv * 16 + (lane & 15);
  bool nv   = node < M;
  int nodec = nv ? node : M - 1;

  f32x4 acc[MBLKS];
  #pragma unroll
  for (int m = 0; m < MBLKS; m++) acc[m] = (f32x4){0.f, 0.f, 0.f, 0.f};

  #pragma unroll
  for (int ks = 0; ks < KSTEPS; ks++){
    int k0 = ks * 32 + quad * 8;
    bf16x8 bfrag;
    if (INF32){
      float4 u = *(const float4*)(Xf + (size_t)nodec * K + k0);
      float4 v = *(const float4*)(Xf + (size_t)nodec * K + k0 + 4);
      i32x4 bi;
      bi.x = (int)(bf16u(u.x) | (bf16u(u.y) << 16));
      bi.y = (int)(bf16u(u.z) | (bf16u(u.w) << 16));
      bi.z = (int)(bf16u(v.x) | (bf16u(v.y) << 16));
      bi.w = (int)(bf16u(v.z) | (bf16u(v.w) << 16));
      bfrag = __builtin_bit_cast(bf16x8, bi);
    } else {
      bfrag = *(const bf16x8*)(Xh + (size_t)nodec * K + k0);
    }
    #pragma unroll
    for (int mb = 0; mb < MBLKS; mb++){
      bf16x8 afrag = *(const bf16x8*)(Wp + ((size_t)(mb * KSTEPS + ks) * 64 + lane) * 8);
      acc[mb] = __builtin_amdgcn_mfma_f32_16x16x32_bf16(afrag, bfrag, acc[mb], 0, 0, 0);
    }
  }

  if (nv){
    unsigned short* crow = Cb + (size_t)node * N;
    #pragma unroll
    for (int mb = 0; mb < MBLKS; mb++){
      uint2 p;
      p.x = bf16u(acc[mb][0]) | (bf16u(acc[mb][1]) << 16);
      p.y = bf16u(acc[mb][2]) | (bf16u(acc[mb][3]) << 16);
      *(uint2*)(crow + mb * 16 + quad * 4) = p;
    }
  }

  float ps[NH], pd[NH];
  #pragma unroll
  for (int h = 0; h < NH; h++){ ps[h] = 0.f; pd[h] = 0.f; }
  #pragma unroll
  for (int mb = 0; mb < MBLKS; mb++){
    int h = (NH == 1) ? 0 : (mb >> 2);
    #pragma unroll
    for (int r = 0; r < 4; r++){
      int c = mb * 16 + quad * 4 + r;
      ps[h] = fmaf(acc[mb][r], asrc[c], ps[h]);
      pd[h] = fmaf(acc[mb][r], adst[c], pd[h]);
    }
  }
  #pragma unroll
  for (int h = 0; h < NH; h++){
    ps[h] += __shfl_xor(ps[h], 16, 64); ps[h] += __shfl_xor(ps[h], 32, 64);
    pd[h] += __shfl_xor(pd[h], 16, 64); pd[h] += __shfl_xor(pd[h], 32, 64);
  }
  if (quad == 0 && nv){
    if (NH == 4){
      *(float4*)(es + (size_t)node * 4) = make_float4(ps[0], ps[1], ps[2], ps[3]);
      *(float4*)(ed + (size_t)node * 4) = make_float4(pd[0], pd[1], pd[2], pd[3]);
    } else {
      es[node] = ps[0];
      ed[node] = pd[0];
    }
  }
}

// ---------------- layer-1 aggregation (bf16 H1 gather, bf16 h1 out) ----------------
DEV void acc4u(uint2 g, float q, float& ax, float& ay, float& az, float& aw){
  ax = fmaf(__uint_as_float(g.x << 16),         q, ax);
  ay = fmaf(__uint_as_float(g.x & 0xffff0000u), q, ay);
  az = fmaf(__uint_as_float(g.y << 16),         q, az);
  aw = fmaf(__uint_as_float(g.y & 0xffff0000u), q, aw);
}

__global__ __launch_bounds__(256) void agg1_kernel(const int* __restrict__ off,
                                                   const int* __restrict__ csr_src,
                                                   const unsigned short* __restrict__ H1b,
                                                   const float* __restrict__ es,
                                                   const float* __restrict__ ed,
                                                   const float* __restrict__ b1,
                                                   const float* __restrict__ lng,
                                                   const float* __restrict__ lnb,
                                                   unsigned short* __restrict__ h1b, int n){
  __shared__ float wshT[4][4][68];   // [wave][head][edge], padded
  __shared__ int   ssh[4][64];
  int wv   = threadIdx.x >> 6;
  int wid  = (blockIdx.x * blockDim.x + threadIdx.x) >> 6;
  int lane = threadIdx.x & 63;
  if (wid >= n) return;
  int s0  = off[wid];
  int deg = off[wid + 1] - s0;
  const float4 edv = *(const float4*)(ed + (size_t)wid * 4);

  float v0, v1, v2, v3;

  if (deg <= 64){
    bool vld = lane < deg;
    int srcl = vld ? csr_src[s0 + lane] : 0;
    float4 e4 = vld ? *(const float4*)(es + (size_t)srcl * 4)
                    : make_float4(-1e30f, -1e30f, -1e30f, -1e30f);
    float e0 = vld ? lrelu(e4.x + edv.x) : -1e30f;
    float e1 = vld ? lrelu(e4.y + edv.y) : -1e30f;
    float e2 = vld ? lrelu(e4.z + edv.z) : -1e30f;
    float e3 = vld ? lrelu(e4.w + edv.w) : -1e30f;
    float m0 = wmaxr(e0), m1 = wmaxr(e1), m2 = wmaxr(e2), m3 = wmaxr(e3);
    float w0 = vld ? __expf(e0 - m0) : 0.f;
    float w1 = vld ? __expf(e1 - m1) : 0.f;
    float w2 = vld ? __expf(e2 - m2) : 0.f;
    float w3 = vld ? __expf(e3 - m3) : 0.f;
    w0 /= (wsum(w0) + 1e-16f);
    w1 /= (wsum(w1) + 1e-16f);
    w2 /= (wsum(w2) + 1e-16f);
    w3 /= (wsum(w3) + 1e-16f);
    ssh[wv][lane] = srcl;
    wshT[wv][0][lane] = w0; wshT[wv][1][lane] = w1;
    wshT[wv][2][lane] = w2; wshT[wv][3][lane] = w3;
    __builtin_amdgcn_wave_barrier();   // same-wave DS in-order; pin compiler order

    int h = lane >> 4;
    const float* wrow = &wshT[wv][h][0];
    int lane4 = lane * 4;
    float ax = 0.f, ay = 0.f, az = 0.f, aw = 0.f;
    int t = 0;
    for (; t + 8 <= deg; t += 8){
      i32x4 sA = *(const i32x4*)&ssh[wv][t];
      i32x4 sB = *(const i32x4*)&ssh[wv][t + 4];
      f32x4 qA = *(const f32x4*)&wrow[t];
      f32x4 qB = *(const f32x4*)&wrow[t + 4];
      uint2 g0 = *(const uint2*)(H1b + (size_t)sA.x * 256 + lane4);
      uint2 g1 = *(const uint2*)(H1b + (size_t)sA.y * 256 + lane4);
      uint2 g2 = *(const uint2*)(H1b + (size_t)sA.z * 256 + lane4);
      uint2 g3 = *(const uint2*)(H1b + (size_t)sA.w * 256 + lane4);
      uint2 g4 = *(const uint2*)(H1b + (size_t)sB.x * 256 + lane4);
      uint2 g5 = *(const uint2*)(H1b + (size_t)sB.y * 256 + lane4);
      uint2 g6 = *(const uint2*)(H1b + (size_t)sB.z * 256 + lane4);
      uint2 g7 = *(const uint2*)(H1b + (size_t)sB.w * 256 + lane4);
      acc4u(g0, qA.x, ax, ay, az, aw);
      acc4u(g1, qA.y, ax, ay, az, aw);
      acc4u(g2, qA.z, ax, ay, az, aw);
      acc4u(g3, qA.w, ax, ay, az, aw);
      acc4u(g4, qB.x, ax, ay, az, aw);
      acc4u(g5, qB.y, ax, ay, az, aw);
      acc4u(g6, qB.z, ax, ay, az, aw);
      acc4u(g7, qB.w, ax, ay, az, aw);
    }
    for (; t < deg; t++){
      int a0 = ssh[wv][t];
      float q0 = wrow[t];
      uint2 g0 = *(const uint2*)(H1b + (size_t)a0 * 256 + lane4);
      acc4u(g0, q0, ax, ay, az, aw);
    }
    float4 bb = *(const float4*)(b1 + lane4);
    v0 = eluf(ax + bb.x); v1 = eluf(ay + bb.y);
    v2 = eluf(az + bb.z); v3 = eluf(aw + bb.w);
    float mu = wsum(v0 + v1 + v2 + v3) * (1.f/256.f);
    float q  = (v0-mu)*(v0-mu) + (v1-mu)*(v1-mu) + (v2-mu)*(v2-mu) + (v3-mu)*(v3-mu);
    float rstd = rsqrtf(wsum(q) * (1.f/256.f) + 1e-5f);
    float4 g4v = *(const float4*)(lng + lane4);
    float4 bo  = *(const float4*)(lnb + lane4);
    uint2 p;
    p.x = bf16u((v0-mu)*rstd*g4v.x + bo.x) | (bf16u((v1-mu)*rstd*g4v.y + bo.y) << 16);
    p.y = bf16u((v2-mu)*rstd*g4v.z + bo.z) | (bf16u((v3-mu)*rstd*g4v.w + bo.w) << 16);
    *(uint2*)(h1b + (size_t)wid * 256 + lane4) = p;
    return;
  }

  // slow path: deg > 64 (rare); lane = channel within head
  float m0 = -1e30f, m1 = -1e30f, m2 = -1e30f, m3 = -1e30f;
  for (int j = lane; j < deg; j += 64){
    int src = csr_src[s0 + j];
    float4 e4 = *(const float4*)(es + (size_t)src * 4);
    m0 = fmaxf(m0, lrelu(e4.x + edv.x));
    m1 = fmaxf(m1, lrelu(e4.y + edv.y));
    m2 = fmaxf(m2, lrelu(e4.z + edv.z));
    m3 = fmaxf(m3, lrelu(e4.w + edv.w));
  }
  m0 = wmaxr(m0); m1 = wmaxr(m1); m2 = wmaxr(m2); m3 = wmaxr(m3);
  float acc0 = 0.f, acc1 = 0.f, acc2 = 0.f, acc3 = 0.f;
  float den0 = 0.f, den1 = 0.f, den2 = 0.f, den3 = 0.f;
  for (int j = 0; j < deg; j++){
    int src = csr_src[s0 + j];
    float4 e4 = *(const float4*)(es + (size_t)src * 4);
    float x0 = __expf(lrelu(e4.x + edv.x) - m0);
    float x1 = __expf(lrelu(e4.y + edv.y) - m1);
    float x2 = __expf(lrelu(e4.z + edv.z) - m2);
    float x3 = __expf(lrelu(e4.w + edv.w) - m3);
    den0 += x0; den1 += x1; den2 += x2; den3 += x3;
    const unsigned short* hp = H1b + (size_t)src * 256;
    acc0 = fmaf(bfl(hp[lane]),       x0, acc0);
    acc1 = fmaf(bfl(hp[64 + lane]),  x1, acc1);
    acc2 = fmaf(bfl(hp[128 + lane]), x2, acc2);
    acc3 = fmaf(bfl(hp[192 + lane]), x3, acc3);
  }
  v0 = eluf(acc0 / (den0 + 1e-16f) + b1[lane]);
  v1 = eluf(acc1 / (den1 + 1e-16f) + b1[64 + lane]);
  v2 = eluf(acc2 / (den2 + 1e-16f) + b1[128 + lane]);
  v3 = eluf(acc3 / (den3 + 1e-16f) + b1[192 + lane]);
  float mu = wsum(v0 + v1 + v2 + v3) * (1.f/256.f);
  float q  = (v0-mu)*(v0-mu) + (v1-mu)*(v1-mu) + (v2-mu)*(v2-mu) + (v3-mu)*(v3-mu);
  float rstd = rsqrtf(wsum(q) * (1.f/256.f) + 1e-5f);
  unsigned short* o = h1b + (size_t)wid * 256;
  o[lane]       = (unsigned short)bf16u((v0-mu)*rstd*lng[lane]       + lnb[lane]);
  o[64 + lane]  = (unsigned short)bf16u((v1-mu)*rstd*lng[64 + lane]  + lnb[64 + lane]);
  o[128 + lane] = (unsigned short)bf16u((v2-mu)*rstd*lng[128 + lane] + lnb[128 + lane]);
  o[192 + lane] = (unsigned short)bf16u((v3-mu)*rstd*lng[192 + lane] + lnb[192 + lane]);
}

// ---------------- layer-2 aggregation (1 head) + fused dueling head ----------------
__global__ __launch_bounds__(256) void agg2_head(const int* __restrict__ off,
                                                 const int* __restrict__ csr_src,
                                                 const int* __restrict__ csr_eid,
                                                 const unsigned short* __restrict__ H2b,
                                                 const float* __restrict__ es,
                                                 const float* __restrict__ ed,
                                                 const float* __restrict__ b2,
                                                 const float* __restrict__ lng,
                                                 const float* __restrict__ lnb,
                                                 const float* __restrict__ semb,
                                                 const int* __restrict__ active,
                                                 const int* __restrict__ stepp,
                                                 const float* __restrict__ fc0w, const float* __restrict__ fc0b,
                                                 const float* __restrict__ fc1w, const float* __restrict__ fc1b,
                                                 const float* __restrict__ fc2w, const float* __restrict__ fc2b,
                                                 const float* __restrict__ fc3w, const float* __restrict__ fc3b,
                                                 const float* __restrict__ valw, const float* __restrict__ valb,
                                                 const float* __restrict__ advw, const float* __restrict__ advb,
                                                 const float* __restrict__ lnhg, const float* __restrict__ lnhb,
                                                 const float* __restrict__ lnfg, const float* __restrict__ lnfb,
                                                 float* __restrict__ h2out,
                                                 float* __restrict__ alpha_out,
                                                 float* __restrict__ logits, int n){
  __shared__ float wsa[4][64];
  __shared__ int   ssa[4][64];
  __shared__ float shh[192];
  int wv   = threadIdx.x >> 6;
  int wid  = (blockIdx.x * blockDim.x + threadIdx.x) >> 6;
  int lane = threadIdx.x & 63;
  if (wid >= n) return;
  int s0  = off[wid];
  int deg = off[wid + 1] - s0;
  float edv = ed[wid];
  int sub = lane & 31, half = lane >> 5;
  const unsigned short* base = H2b + sub * 2;
  float va, vb;

  if (deg <= 64){
    bool vld = lane < deg;
    int srcl = vld ? csr_src[s0 + lane] : 0;
    float el = vld ? lrelu(es[srcl] + edv) : -1e30f;
    float m  = wmaxr(el);
    float w  = vld ? __expf(el - m) : 0.f;
    float den = wsum(w) + 1e-16f;
    float wl = w / den;
    if (vld) alpha_out[csr_eid[s0 + lane]] = wl;
    ssa[wv][lane] = srcl;
    wsa[wv][lane] = vld ? wl : 0.f;
    __builtin_amdgcn_wave_barrier();

    float a0 = 0.f, a1 = 0.f;
    int nsteps = (deg + 1) >> 1;
    int j = 0;
    for (; j + 4 <= nsteps; j += 4){
      int e0 = 2 * j + half;
      int sA = ssa[wv][e0],     sB = ssa[wv][e0 + 2];
      int sC = ssa[wv][e0 + 4], sD = ssa[wv][e0 + 6];
      float wA = wsa[wv][e0],     wB = wsa[wv][e0 + 2];
      float wC = wsa[wv][e0 + 4], wD = wsa[wv][e0 + 6];
      unsigned int gA = *(const unsigned int*)(base + (size_t)sA * 64);
      unsigned int gB = *(const unsigned int*)(base + (size_t)sB * 64);
      unsigned int gC = *(const unsigned int*)(base + (size_t)sC * 64);
      unsigned int gD = *(const unsigned int*)(base + (size_t)sD * 64);
      a0 = fmaf(__uint_as_float(gA << 16),         wA, a0);
      a1 = fmaf(__uint_as_float(gA & 0xffff0000u), wA, a1);
      a0 = fmaf(__uint_as_float(gB << 16),         wB, a0);
      a1 = fmaf(__uint_as_float(gB & 0xffff0000u), wB, a1);
      a0 = fmaf(__uint_as_float(gC << 16),         wC, a0);
      a1 = fmaf(__uint_as_float(gC & 0xffff0000u), wC, a1);
      a0 = fmaf(__uint_as_float(gD << 16),         wD, a0);
      a1 = fmaf(__uint_as_float(gD & 0xffff0000u), wD, a1);
    }
    for (; j < nsteps; j++){
      int e = 2 * j + half;
      int sA = ssa[wv][e];
      float wA = wsa[wv][e];
      unsigned int g = *(const unsigned int*)(base + (size_t)sA * 64);
      a0 = fmaf(__uint_as_float(g << 16),         wA, a0);
      a1 = fmaf(__uint_as_float(g & 0xffff0000u), wA, a1);
    }
    a0 += __shfl_xor(a0, 32, 64);
    a1 += __shfl_xor(a1, 32, 64);
    va = a0 + b2[2 * sub];
    vb = a1 + b2[2 * sub + 1];
  } else {
    // slow path: all lanes process all edges (halves duplicate — harmless)
    float m = -1e30f;
    for (int j2 = lane; j2 < deg; j2 += 64)
      m = fmaxf(m, lrelu(es[csr_src[s0 + j2]] + edv));
    m = wmaxr(m);
    float den = 0.f;
    for (int j2 = lane; j2 < deg; j2 += 64)
      den += __expf(lrelu(es[csr_src[s0 + j2]] + edv) - m);
    den = wsum(den) + 1e-16f;
    float a0 = 0.f, a1 = 0.f;
    for (int j2 = 0; j2 < deg; j2++){
      int srcj = csr_src[s0 + j2];
      float a = __expf(lrelu(es[srcj] + edv) - m) / den;
      if (lane == 0) alpha_out[csr_eid[s0 + j2]] = a;
      unsigned int g = *(const unsigned int*)(base + (size_t)srcj * 64);
      a0 = fmaf(__uint_as_float(g << 16),         a, a0);
      a1 = fmaf(__uint_as_float(g & 0xffff0000u), a, a1);
    }
    va = a0 + b2[2 * sub];
    vb = a1 + b2[2 * sub + 1];
  }

  // LN over 64 ch (each pair appears twice across lanes -> /128)
  float mu = wsum(va + vb) * (1.f/128.f);
  float d0 = va - mu, d1 = vb - mu;
  float rstd = rsqrtf(wsum(d0*d0 + d1*d1) * (1.f/128.f) + 1e-5f);
  float n0v = d0 * rstd * lng[2 * sub]     + lnb[2 * sub];
  float n1v = d1 * rstd * lng[2 * sub + 1] + lnb[2 * sub + 1];
  if (half == 0)
    *(float2*)(h2out + (size_t)wid * 64 + 2 * sub) = make_float2(n0v, n1v);

  // ---- fused dueling head: the wave owning the active node finishes the net ----
  if (wid == active[0]){
    int t = lane;
    // reconstruct h2[active][t] from pair layout
    float ra = __shfl(n0v, t >> 1, 64);
    float rb = __shfl(n1v, t >> 1, 64);
    float h2t = (t & 1) ? rb : ra;

    float sval = (float)(stepp[0] + 1) * 0.01f;
    float stepsv = ln64(fmaxf(fmaf(sval, fc0w[t], fc0b[t]), 0.f), lnhg, lnhb, t);

    float acc = fc1b[t];
    #pragma unroll 8
    for (int k = 0; k < 768; k++) acc = fmaf(semb[k], fc1w[k * 64 + t], acc);
    float sentv = ln64(fmaxf(acc, 0.f), lnhg, lnhb, t) + stepsv;
    shh[t] = sentv;
    __builtin_amdgcn_wave_barrier();
    float acc2 = fc2b[t];
    #pragma unroll 8
    for (int k = 0; k < 64; k++) acc2 = fmaf(shh[k], fc2w[k * 64 + t], acc2);
    __builtin_amdgcn_wave_barrier();
    float sent2 = ln64(fmaxf(acc2, 0.f), lnhg, lnhb, t);

    float c0 = h2t, c1 = sent2;
    float mu2 = wsum(c0 + c1) * (1.f/128.f);
    float q2  = (c0-mu2)*(c0-mu2) + (c1-mu2)*(c1-mu2);
    float rs2 = rsqrtf(wsum(q2) * (1.f/128.f) + 1e-5f);
    shh[t]      = (c0-mu2)*rs2*lnfg[t]      + lnfb[t];
    shh[64 + t] = (c1-mu2)*rs2*lnfg[64 + t] + lnfb[64 + t];
    __builtin_amdgcn_wave_barrier();

    float acc3 = fc3b[t];
    #pragma unroll 8
    for (int k = 0; k < 128; k++) acc3 = fmaf(shh[k], fc3w[k * 64 + t], acc3);
    float a2v = ln64(fmaxf(acc3, 0.f), lnhg, lnhb, t);
    shh[128 + t] = a2v;
    __builtin_amdgcn_wave_barrier();

    float val = wsum(a2v * valw[t]) + valb[0];
    float advv = 0.f;
    if (t < 32){
      advv = advb[t];
      #pragma unroll 8
      for (int k = 0; k < 64; k++) advv = fmaf(shh[128 + k], advw[k * 32 + t], advv);
    }
    float am = wsum(t < 32 ? advv : 0.f) * (1.f/32.f);
    if (t < 32) logits[t] = tanhf(val + advv - am);
  }
}

extern "C" void kernel_launch(void* const* d_in, const int* in_sizes, int n_in,
                              void* d_out, int out_size, void* d_ws, size_t ws_size,
                              hipStream_t stream) {
  const float* x     = (const float*)d_in[0];
  const int*   ei    = (const int*)  d_in[1];
  const float* semb  = (const float*)d_in[2];
  const int*   act   = (const int*)  d_in[3];
  const int*   step  = (const int*)  d_in[4];
  const float* W1    = (const float*)d_in[5];
  const float* as1   = (const float*)d_in[6];
  const float* ad1   = (const float*)d_in[7];
  const float* b1    = (const float*)d_in[8];
  const float* W2    = (const float*)d_in[9];
  const float* as2   = (const float*)d_in[10];
  const float* ad2   = (const float*)d_in[11];
  const float* b2    = (const float*)d_in[12];
  const float* fc0w  = (const float*)d_in[13];
  const float* fc0b  = (const float*)d_in[14];
  const float* fc1w  = (const float*)d_in[15];
  const float* fc1b  = (const float*)d_in[16];
  const float* fc2w  = (const float*)d_in[17];
  const float* fc2b  = (const float*)d_in[18];
  const float* fc3w  = (const float*)d_in[19];
  const float* fc3b  = (const float*)d_in[20];
  const float* valw  = (const float*)d_in[21];
  const float* valb  = (const float*)d_in[22];
  const float* advw  = (const float*)d_in[23];
  const float* advb  = (const float*)d_in[24];
  const float* lnhg  = (const float*)d_in[25];
  const float* lnhb  = (const float*)d_in[26];
  const float* lnfg  = (const float*)d_in[27];
  const float* lnfb  = (const float*)d_in[28];
  const float* lnag  = (const float*)d_in[29];
  const float* lnab  = (const float*)d_in[30];

  char* ws = (char*)d_ws;
  size_t o = 0;
  auto alloc = [&](size_t bytes) -> void* {
    o = (o + 255) & ~(size_t)255;
    void* p = ws + o;
    o += bytes;
    return p;
  };
  int*   deg     = (int*)  alloc((size_t)(NN + 1) * 4);
  int*   off     = (int*)  alloc((size_t)(NN + 1) * 4);
  int*   cur     = (int*)  alloc((size_t)NN * 4);
  int*   bsum    = (int*)  alloc((size_t)(SCAN_NB + 1) * 4);
  int*   csr_src = (int*)  alloc((size_t)ET * 4);
  int*   csr_eid = (int*)  alloc((size_t)ET * 4);
  short* Wp1     = (short*)alloc((size_t)4096 * 8 * 2);   // 64 KB
  short* Wp2     = (short*)alloc((size_t)2048 * 8 * 2);   // 32 KB
  unsigned short* H1b = (unsigned short*)alloc((size_t)NN * 256 * 2);  // bf16 H1
  unsigned short* h1b = (unsigned short*)alloc((size_t)NN * 256 * 2);  // bf16 h1 (post agg1)
  float* es1     = (float*)alloc((size_t)NN * 16);
  float* ed1     = (float*)alloc((size_t)NN * 16);
  unsigned short* H2b = H1b;   // aliases; lifetimes don't overlap
  float* es2 = es1;
  float* ed2 = ed1;

  float* logits    = (float*)d_out;
  float* h2out     = (float*)d_out + 32;
  float* alpha_out = (float*)d_out + 32 + (size_t)NN * 64;

  // CSR build (full-grid kernels; atomics need the parallelism)
  hipMemsetAsync(deg, 0, (size_t)NN * 4, stream);
  degree_kernel<<<(ET + 255) / 256, 256, 0, stream>>>(ei, deg);
  scan_part<<<SCAN_NB, 256, 0, stream>>>(deg, off, bsum, NN);
  scan_top <<<1, 64, 0, stream>>>(bsum, SCAN_NB);
  scan_add <<<SCAN_NB, 256, 0, stream>>>(off, cur, bsum, NN, SCAN_NB);
  fill_csr<<<(ET + 255) / 256, 256, 0, stream>>>(ei, cur, csr_src, csr_eid);
  pack_both<<<24, 256, 0, stream>>>(W1, W2, Wp1, Wp2);

  // layer 1: MFMA GEMM + fused att dots
  mfma_gemm_att<4, 16, 4, true><<<(NN + 63) / 64, 256, 0, stream>>>(
      Wp1, x, nullptr, H1b, as1, ad1, es1, ed1, NN);
  agg1_kernel<<<NN / 4, 256, 0, stream>>>(off, csr_src, H1b, es1, ed1, b1, lnag, lnab, h1b, NN);

  // layer 2
  mfma_gemm_att<8, 4, 1, false><<<(NN + 63) / 64, 256, 0, stream>>>(
      Wp2, nullptr, h1b, H2b, as2, ad2, es2, ed2, NN);
  agg2_head<<<NN / 4, 256, 0, stream>>>(off, csr_src, csr_eid, H2b, es2, ed2, b2,
                                        lnhg, lnhb,
                                        semb, act, step,
                                        fc0w, fc0b, fc1w, fc1b, fc2w, fc2b, fc3w, fc3b,
                                        valw, valb, advw, advb,
                                        lnhg, lnhb, lnfg, lnfb,
                                        h2out, alpha_out, logits, NN);
}

// Round 8
// 367.821 us; speedup vs baseline: 1.5000x; 1.0116x over previous
//
#include <hip/hip_runtime.h>
#include <cstdint>
#include <cstddef>

#define DEV __device__ __forceinline__

static constexpr int NN  = 50000;
static constexpr int EE  = 600000;
static constexpr int ET  = 650000;   // EE + NN self loops
static constexpr int SCAN_CHUNK = 1024;                 // 256 threads x 4
static constexpr int SCAN_NB = (NN + SCAN_CHUNK - 1) / SCAN_CHUNK;   // 49

typedef __attribute__((ext_vector_type(8))) short bf16x8;   // 8 bf16 (4 VGPR)
typedef __attribute__((ext_vector_type(4))) float f32x4;    // MFMA acc
typedef __attribute__((ext_vector_type(4))) int   i32x4;

DEV float wsum(float v){
  #pragma unroll
  for (int o = 32; o > 0; o >>= 1) v += __shfl_xor(v, o, 64);
  return v;
}
DEV float wmaxr(float v){
  #pragma unroll
  for (int o = 32; o > 0; o >>= 1) v = fmaxf(v, __shfl_xor(v, o, 64));
  return v;
}
DEV float lrelu(float x){ return x > 0.f ? x : 0.2f * x; }
DEV float eluf(float x){ return x > 0.f ? x : expm1f(x); }
DEV float ln64(float v, const float* g, const float* b, int lane){
  float mu  = wsum(v) * (1.f/64.f);
  float d   = v - mu;
  float var = wsum(d*d) * (1.f/64.f);
  return d * rsqrtf(var + 1e-5f) * g[lane] + b[lane];
}
// f32 -> bf16 (RNE) as raw ushort bits
DEV unsigned int bf16u(float f){
  unsigned int u = __float_as_uint(f);
  return (u + 0x7fffu + ((u >> 16) & 1u)) >> 16;
}
DEV float bfl(unsigned int lo16){ return __uint_as_float(lo16 << 16); }

// ---------------- CSR build (full-occupancy separate kernels) ----------------
__global__ void degree_kernel(const int* __restrict__ ei, int* __restrict__ deg){
  int e = blockIdx.x * blockDim.x + threadIdx.x;
  if (e >= ET) return;
  int dst = (e < EE) ? ei[EE + e] : (e - EE);
  atomicAdd(&deg[dst], 1);
}

__global__ __launch_bounds__(256) void scan_part(const int* __restrict__ deg,
                                                 int* __restrict__ off,
                                                 int* __restrict__ bsum, int n){
  __shared__ int wtot[4];
  int tid = threadIdx.x, lane = tid & 63, w = tid >> 6;
  int i0 = blockIdx.x * SCAN_CHUNK + tid * 4;
  int v[4], s = 0;
  #pragma unroll
  for (int p = 0; p < 4; p++){ int i = i0 + p; v[p] = (i < n) ? deg[i] : 0; s += v[p]; }
  int sc = s;
  #pragma unroll
  for (int d = 1; d < 64; d <<= 1){ int t = __shfl_up(sc, d, 64); if (lane >= d) sc += t; }
  if (lane == 63) wtot[w] = sc;
  __syncthreads();
  int woff = 0;
  #pragma unroll
  for (int k = 0; k < 4; k++) if (k < w) woff += wtot[k];
  int excl = woff + sc - s;
  #pragma unroll
  for (int p = 0; p < 4; p++){
    int i = i0 + p;
    if (i < n) off[i] = excl;
    excl += v[p];
  }
  if (tid == 0) bsum[blockIdx.x] = wtot[0] + wtot[1] + wtot[2] + wtot[3];
}

__global__ __launch_bounds__(64) void scan_top(int* __restrict__ bsum, int nb){
  int lane = threadIdx.x;
  int v = (lane < nb) ? bsum[lane] : 0;
  int sc = v;
  #pragma unroll
  for (int d = 1; d < 64; d <<= 1){ int t = __shfl_up(sc, d, 64); if (lane >= d) sc += t; }
  if (lane < nb) bsum[lane] = sc - v;
  if (lane == 63) bsum[nb] = sc;    // grand total
}

__global__ __launch_bounds__(256) void scan_add(int* __restrict__ off,
                                                int* __restrict__ cur,
                                                const int* __restrict__ bsum, int n, int nb){
  int i0 = blockIdx.x * SCAN_CHUNK + threadIdx.x * 4;
  int add = bsum[blockIdx.x];
  #pragma unroll
  for (int p = 0; p < 4; p++){
    int j = i0 + p;
    if (j < n){ int t = off[j] + add; off[j] = t; cur[j] = t; }
  }
  if (blockIdx.x == 0 && threadIdx.x == 0) off[n] = bsum[nb];
}

__global__ void fill_csr(const int* __restrict__ ei, int* __restrict__ cur,
                         int* __restrict__ csr_src, int* __restrict__ csr_eid){
  int e = blockIdx.x * blockDim.x + threadIdx.x;
  if (e >= ET) return;
  int src, dst;
  if (e < EE){ src = ei[e]; dst = ei[EE + e]; } else { src = dst = e - EE; }
  int pos = atomicAdd(&cur[dst], 1);
  csr_src[pos] = src;
  csr_eid[pos] = e;
}

// pack W1 (4096 frag-threads) and W2 (2048 frag-threads) in one dispatch
__global__ __launch_bounds__(256) void pack_both(const float* __restrict__ W1,
                                                 const float* __restrict__ W2,
                                                 short* __restrict__ Wp1,
                                                 short* __restrict__ Wp2){
  int tid = blockIdx.x * 256 + threadIdx.x;
  if (tid < 4096){               // W1: K=128 (ksteps=4), N=256
    int lane = tid & 63, ks = (tid >> 6) & 3, mb = tid >> 8;
    int col  = mb * 16 + (lane & 15);
    int krow = ks * 32 + (lane >> 4) * 8;
    #pragma unroll
    for (int j = 0; j < 8; j++)
      Wp1[(size_t)tid * 8 + j] = (short)bf16u(W1[(size_t)(krow + j) * 256 + col]);
  } else if (tid < 4096 + 2048){ // W2: K=256 (ksteps=8), N=64
    int t2 = tid - 4096;
    int lane = t2 & 63, ks = (t2 >> 6) & 7, mb = t2 >> 9;
    int col  = mb * 16 + (lane & 15);
    int krow = ks * 32 + (lane >> 4) * 8;
    #pragma unroll
    for (int j = 0; j < 8; j++)
      Wp2[(size_t)t2 * 8 + j] = (short)bf16u(W2[(size_t)(krow + j) * 64 + col]);
  }
}

// ---------------- MFMA GEMM (LDS-free) + bf16 C-store + fused att dots ----------------
template<int KSTEPS, int MBLKS, int NH, bool INF32>
__global__ __launch_bounds__(256) void mfma_gemm_att(const short* __restrict__ Wp,
                                                     const float* __restrict__ Xf,
                                                     const unsigned short* __restrict__ Xh,
                                                     unsigned short* __restrict__ Cb,
                                                     const float* __restrict__ asrc,
                                                     const float* __restrict__ adst,
                                                     float* __restrict__ es,
                                                     float* __restrict__ ed, int M){
  constexpr int K = KSTEPS * 32, N = MBLKS * 16;
  int lane  = threadIdx.x & 63;
  int wv    = threadIdx.x >> 6;
  int quad  = lane >> 4;
  int node  = blockIdx.x * 64 + wv * 16 + (lane & 15);
  bool nv   = node < M;
  int nodec = nv ? node : M - 1;

  f32x4 acc[MBLKS];
  #pragma unroll
  for (int m = 0; m < MBLKS; m++) acc[m] = (f32x4){0.f, 0.f, 0.f, 0.f};

  #pragma unroll
  for (int ks = 0; ks < KSTEPS; ks++){
    int k0 = ks * 32 + quad * 8;
    bf16x8 bfrag;
    if (INF32){
      float4 u = *(const float4*)(Xf + (size_t)nodec * K + k0);
      float4 v = *(const float4*)(Xf + (size_t)nodec * K + k0 + 4);
      i32x4 bi;
      bi.x = (int)(bf16u(u.x) | (bf16u(u.y) << 16));
      bi.y = (int)(bf16u(u.z) | (bf16u(u.w) << 16));
      bi.z = (int)(bf16u(v.x) | (bf16u(v.y) << 16));
      bi.w = (int)(bf16u(v.z) | (bf16u(v.w) << 16));
      bfrag = __builtin_bit_cast(bf16x8, bi);
    } else {
      bfrag = *(const bf16x8*)(Xh + (size_t)nodec * K + k0);
    }
    #pragma unroll
    for (int mb = 0; mb < MBLKS; mb++){
      bf16x8 afrag = *(const bf16x8*)(Wp + ((size_t)(mb * KSTEPS + ks) * 64 + lane) * 8);
      acc[mb] = __builtin_amdgcn_mfma_f32_16x16x32_bf16(afrag, bfrag, acc[mb], 0, 0, 0);
    }
  }

  if (nv){
    unsigned short* crow = Cb + (size_t)node * N;
    #pragma unroll
    for (int mb = 0; mb < MBLKS; mb++){
      uint2 p;
      p.x = bf16u(acc[mb][0]) | (bf16u(acc[mb][1]) << 16);
      p.y = bf16u(acc[mb][2]) | (bf16u(acc[mb][3]) << 16);
      *(uint2*)(crow + mb * 16 + quad * 4) = p;
    }
  }

  float ps[NH], pd[NH];
  #pragma unroll
  for (int h = 0; h < NH; h++){ ps[h] = 0.f; pd[h] = 0.f; }
  #pragma unroll
  for (int mb = 0; mb < MBLKS; mb++){
    int h = (NH == 1) ? 0 : (mb >> 2);
    #pragma unroll
    for (int r = 0; r < 4; r++){
      int c = mb * 16 + quad * 4 + r;
      ps[h] = fmaf(acc[mb][r], asrc[c], ps[h]);
      pd[h] = fmaf(acc[mb][r], adst[c], pd[h]);
    }
  }
  #pragma unroll
  for (int h = 0; h < NH; h++){
    ps[h] += __shfl_xor(ps[h], 16, 64); ps[h] += __shfl_xor(ps[h], 32, 64);
    pd[h] += __shfl_xor(pd[h], 16, 64); pd[h] += __shfl_xor(pd[h], 32, 64);
  }
  if (quad == 0 && nv){
    if (NH == 4){
      *(float4*)(es + (size_t)node * 4) = make_float4(ps[0], ps[1], ps[2], ps[3]);
      *(float4*)(ed + (size_t)node * 4) = make_float4(pd[0], pd[1], pd[2], pd[3]);
    } else {
      es[node] = ps[0];
      ed[node] = pd[0];
    }
  }
}

// ---------------- layer-1 aggregation (bf16 H1 gather, bf16 h1 out) ----------------
DEV void acc4u(uint2 g, float q, float& ax, float& ay, float& az, float& aw){
  ax = fmaf(__uint_as_float(g.x << 16),         q, ax);
  ay = fmaf(__uint_as_float(g.x & 0xffff0000u), q, ay);
  az = fmaf(__uint_as_float(g.y << 16),         q, az);
  aw = fmaf(__uint_as_float(g.y & 0xffff0000u), q, aw);
}

__global__ __launch_bounds__(256) void agg1_kernel(const int* __restrict__ off,
                                                   const int* __restrict__ csr_src,
                                                   const unsigned short* __restrict__ H1b,
                                                   const float* __restrict__ es,
                                                   const float* __restrict__ ed,
                                                   const float* __restrict__ b1,
                                                   const float* __restrict__ lng,
                                                   const float* __restrict__ lnb,
                                                   unsigned short* __restrict__ h1b, int n){
  __shared__ float wshT[4][4][68];   // [wave][head][edge], padded
  __shared__ int   ssh[4][64];
  int wv   = threadIdx.x >> 6;
  int wid  = (blockIdx.x * blockDim.x + threadIdx.x) >> 6;
  int lane = threadIdx.x & 63;
  if (wid >= n) return;
  int s0  = off[wid];
  int deg = off[wid + 1] - s0;
  const float4 edv = *(const float4*)(ed + (size_t)wid * 4);

  float v0, v1, v2, v3;

  if (deg <= 64){
    bool vld = lane < deg;
    int srcl = vld ? csr_src[s0 + lane] : 0;
    float4 e4 = vld ? *(const float4*)(es + (size_t)srcl * 4)
                    : make_float4(-1e30f, -1e30f, -1e30f, -1e30f);
    float e0 = vld ? lrelu(e4.x + edv.x) : -1e30f;
    float e1 = vld ? lrelu(e4.y + edv.y) : -1e30f;
    float e2 = vld ? lrelu(e4.z + edv.z) : -1e30f;
    float e3 = vld ? lrelu(e4.w + edv.w) : -1e30f;
    float m0 = wmaxr(e0), m1 = wmaxr(e1), m2 = wmaxr(e2), m3 = wmaxr(e3);
    float w0 = vld ? __expf(e0 - m0) : 0.f;
    float w1 = vld ? __expf(e1 - m1) : 0.f;
    float w2 = vld ? __expf(e2 - m2) : 0.f;
    float w3 = vld ? __expf(e3 - m3) : 0.f;
    w0 /= (wsum(w0) + 1e-16f);
    w1 /= (wsum(w1) + 1e-16f);
    w2 /= (wsum(w2) + 1e-16f);
    w3 /= (wsum(w3) + 1e-16f);
    ssh[wv][lane] = srcl;
    wshT[wv][0][lane] = w0; wshT[wv][1][lane] = w1;
    wshT[wv][2][lane] = w2; wshT[wv][3][lane] = w3;
    __builtin_amdgcn_wave_barrier();   // same-wave DS in-order; pin compiler order

    int h = lane >> 4;
    const float* wrow = &wshT[wv][h][0];
    int lane4 = lane * 4;
    float ax = 0.f, ay = 0.f, az = 0.f, aw = 0.f;
    int t = 0;
    for (; t + 8 <= deg; t += 8){
      i32x4 sA = *(const i32x4*)&ssh[wv][t];
      i32x4 sB = *(const i32x4*)&ssh[wv][t + 4];
      f32x4 qA = *(const f32x4*)&wrow[t];
      f32x4 qB = *(const f32x4*)&wrow[t + 4];
      uint2 g0 = *(const uint2*)(H1b + (size_t)sA.x * 256 + lane4);
      uint2 g1 = *(const uint2*)(H1b + (size_t)sA.y * 256 + lane4);
      uint2 g2 = *(const uint2*)(H1b + (size_t)sA.z * 256 + lane4);
      uint2 g3 = *(const uint2*)(H1b + (size_t)sA.w * 256 + lane4);
      uint2 g4 = *(const uint2*)(H1b + (size_t)sB.x * 256 + lane4);
      uint2 g5 = *(const uint2*)(H1b + (size_t)sB.y * 256 + lane4);
      uint2 g6 = *(const uint2*)(H1b + (size_t)sB.z * 256 + lane4);
      uint2 g7 = *(const uint2*)(H1b + (size_t)sB.w * 256 + lane4);
      acc4u(g0, qA.x, ax, ay, az, aw);
      acc4u(g1, qA.y, ax, ay, az, aw);
      acc4u(g2, qA.z, ax, ay, az, aw);
      acc4u(g3, qA.w, ax, ay, az, aw);
      acc4u(g4, qB.x, ax, ay, az, aw);
      acc4u(g5, qB.y, ax, ay, az, aw);
      acc4u(g6, qB.z, ax, ay, az, aw);
      acc4u(g7, qB.w, ax, ay, az, aw);
    }
    for (; t < deg; t++){
      int a0 = ssh[wv][t];
      float q0 = wrow[t];
      uint2 g0 = *(const uint2*)(H1b + (size_t)a0 * 256 + lane4);
      acc4u(g0, q0, ax, ay, az, aw);
    }
    float4 bb = *(const float4*)(b1 + lane4);
    v0 = eluf(ax + bb.x); v1 = eluf(ay + bb.y);
    v2 = eluf(az + bb.z); v3 = eluf(aw + bb.w);
    float mu = wsum(v0 + v1 + v2 + v3) * (1.f/256.f);
    float q  = (v0-mu)*(v0-mu) + (v1-mu)*(v1-mu) + (v2-mu)*(v2-mu) + (v3-mu)*(v3-mu);
    float rstd = rsqrtf(wsum(q) * (1.f/256.f) + 1e-5f);
    float4 g4v = *(const float4*)(lng + lane4);
    float4 bo  = *(const float4*)(lnb + lane4);
    uint2 p;
    p.x = bf16u((v0-mu)*rstd*g4v.x + bo.x) | (bf16u((v1-mu)*rstd*g4v.y + bo.y) << 16);
    p.y = bf16u((v2-mu)*rstd*g4v.z + bo.z) | (bf16u((v3-mu)*rstd*g4v.w + bo.w) << 16);
    *(uint2*)(h1b + (size_t)wid * 256 + lane4) = p;
    return;
  }

  // slow path: deg > 64 (rare); lane = channel within head
  float m0 = -1e30f, m1 = -1e30f, m2 = -1e30f, m3 = -1e30f;
  for (int j = lane; j < deg; j += 64){
    int src = csr_src[s0 + j];
    float4 e4 = *(const float4*)(es + (size_t)src * 4);
    m0 = fmaxf(m0, lrelu(e4.x + edv.x));
    m1 = fmaxf(m1, lrelu(e4.y + edv.y));
    m2 = fmaxf(m2, lrelu(e4.z + edv.z));
    m3 = fmaxf(m3, lrelu(e4.w + edv.w));
  }
  m0 = wmaxr(m0); m1 = wmaxr(m1); m2 = wmaxr(m2); m3 = wmaxr(m3);
  float acc0 = 0.f, acc1 = 0.f, acc2 = 0.f, acc3 = 0.f;
  float den0 = 0.f, den1 = 0.f, den2 = 0.f, den3 = 0.f;
  for (int j = 0; j < deg; j++){
    int src = csr_src[s0 + j];
    float4 e4 = *(const float4*)(es + (size_t)src * 4);
    float x0 = __expf(lrelu(e4.x + edv.x) - m0);
    float x1 = __expf(lrelu(e4.y + edv.y) - m1);
    float x2 = __expf(lrelu(e4.z + edv.z) - m2);
    float x3 = __expf(lrelu(e4.w + edv.w) - m3);
    den0 += x0; den1 += x1; den2 += x2; den3 += x3;
    const unsigned short* hp = H1b + (size_t)src * 256;
    acc0 = fmaf(bfl(hp[lane]),       x0, acc0);
    acc1 = fmaf(bfl(hp[64 + lane]),  x1, acc1);
    acc2 = fmaf(bfl(hp[128 + lane]), x2, acc2);
    acc3 = fmaf(bfl(hp[192 + lane]), x3, acc3);
  }
  v0 = eluf(acc0 / (den0 + 1e-16f) + b1[lane]);
  v1 = eluf(acc1 / (den1 + 1e-16f) + b1[64 + lane]);
  v2 = eluf(acc2 / (den2 + 1e-16f) + b1[128 + lane]);
  v3 = eluf(acc3 / (den3 + 1e-16f) + b1[192 + lane]);
  float mu = wsum(v0 + v1 + v2 + v3) * (1.f/256.f);
  float q  = (v0-mu)*(v0-mu) + (v1-mu)*(v1-mu) + (v2-mu)*(v2-mu) + (v3-mu)*(v3-mu);
  float rstd = rsqrtf(wsum(q) * (1.f/256.f) + 1e-5f);
  unsigned short* o = h1b + (size_t)wid * 256;
  o[lane]       = (unsigned short)bf16u((v0-mu)*rstd*lng[lane]       + lnb[lane]);
  o[64 + lane]  = (unsigned short)bf16u((v1-mu)*rstd*lng[64 + lane]  + lnb[64 + lane]);
  o[128 + lane] = (unsigned short)bf16u((v2-mu)*rstd*lng[128 + lane] + lnb[128 + lane]);
  o[192 + lane] = (unsigned short)bf16u((v3-mu)*rstd*lng[192 + lane] + lnb[192 + lane]);
}

// ---------------- layer-2 aggregation (R5-proven loop: lane=channel, shfl bcast)
// + fused dueling head (lane t holds h2[wid][t] directly) ----------------
__global__ __launch_bounds__(256) void agg2_head(const int* __restrict__ off,
                                                 const int* __restrict__ csr_src,
                                                 const int* __restrict__ csr_eid,
                                                 const unsigned short* __restrict__ H2b,
                                                 const float* __restrict__ es,
                                                 const float* __restrict__ ed,
                                                 const float* __restrict__ b2,
                                                 const float* __restrict__ lng,
                                                 const float* __restrict__ lnb,
                                                 const float* __restrict__ semb,
                                                 const int* __restrict__ active,
                                                 const int* __restrict__ stepp,
                                                 const float* __restrict__ fc0w, const float* __restrict__ fc0b,
                                                 const float* __restrict__ fc1w, const float* __restrict__ fc1b,
                                                 const float* __restrict__ fc2w, const float* __restrict__ fc2b,
                                                 const float* __restrict__ fc3w, const float* __restrict__ fc3b,
                                                 const float* __restrict__ valw, const float* __restrict__ valb,
                                                 const float* __restrict__ advw, const float* __restrict__ advb,
                                                 const float* __restrict__ lnhg, const float* __restrict__ lnhb,
                                                 const float* __restrict__ lnfg, const float* __restrict__ lnfb,
                                                 float* __restrict__ h2out,
                                                 float* __restrict__ alpha_out,
                                                 float* __restrict__ logits, int n){
  __shared__ float shh[192];
  int wid  = (blockIdx.x * blockDim.x + threadIdx.x) >> 6;
  int lane = threadIdx.x & 63;
  if (wid >= n) return;
  int s0  = off[wid];
  int deg = off[wid + 1] - s0;
  float edv = ed[wid];
  float acc = 0.f;

  if (deg <= 64){
    bool vld = lane < deg;
    int srcl = vld ? csr_src[s0 + lane] : 0;
    float el = vld ? lrelu(es[srcl] + edv) : -1e30f;
    float m  = wmaxr(el);
    float w  = vld ? __expf(el - m) : 0.f;
    float den = wsum(w) + 1e-16f;
    float wl = w / den;
    if (vld) alpha_out[csr_eid[s0 + lane]] = wl;
    int t = 0;
    for (; t + 4 <= deg; t += 4){
      int a0 = __shfl(srcl, t, 64),   a1 = __shfl(srcl, t+1, 64);
      int a2 = __shfl(srcl, t+2, 64), a3 = __shfl(srcl, t+3, 64);
      float q0 = __shfl(wl, t, 64),   q1 = __shfl(wl, t+1, 64);
      float q2 = __shfl(wl, t+2, 64), q3 = __shfl(wl, t+3, 64);
      float h0 = bfl(H2b[(size_t)a0 * 64 + lane]);
      float h1v = bfl(H2b[(size_t)a1 * 64 + lane]);
      float h2v = bfl(H2b[(size_t)a2 * 64 + lane]);
      float h3 = bfl(H2b[(size_t)a3 * 64 + lane]);
      acc = fmaf(h0, q0, acc); acc = fmaf(h1v, q1, acc);
      acc = fmaf(h2v, q2, acc); acc = fmaf(h3, q3, acc);
    }
    for (; t < deg; t++){
      int a0 = __shfl(srcl, t, 64);
      float q0 = __shfl(wl, t, 64);
      acc = fmaf(bfl(H2b[(size_t)a0 * 64 + lane]), q0, acc);
    }
  } else {
    float m = -1e30f;
    for (int j = lane; j < deg; j += 64){
      int src = csr_src[s0 + j];
      m = fmaxf(m, lrelu(es[src] + edv));
    }
    m = wmaxr(m);
    float den = 0.f;
    for (int j = lane; j < deg; j += 64){
      int src = csr_src[s0 + j];
      den += __expf(lrelu(es[src] + edv) - m);
    }
    den = wsum(den) + 1e-16f;
    for (int j = 0; j < deg; j++){
      int src = csr_src[s0 + j];
      float a = __expf(lrelu(es[src] + edv) - m) / den;
      if (lane == 0) alpha_out[csr_eid[s0 + j]] = a;
      acc = fmaf(bfl(H2b[(size_t)src * 64 + lane]), a, acc);
    }
  }
  float v  = acc + b2[lane];
  float mu = wsum(v) * (1.f/64.f);
  float d  = v - mu;
  float rstd = rsqrtf(wsum(d*d) * (1.f/64.f) + 1e-5f);
  float h2v = d * rstd * lng[lane] + lnb[lane];
  h2out[(size_t)wid * 64 + lane] = h2v;

  // ---- fused dueling head: the wave owning the active node finishes the net ----
  if (wid == active[0]){
    int t = lane;   // lane t holds h2[active][t] == h2v

    float sval = (float)(stepp[0] + 1) * 0.01f;
    float stepsv = ln64(fmaxf(fmaf(sval, fc0w[t], fc0b[t]), 0.f), lnhg, lnhb, t);

    float acc1h = fc1b[t];
    #pragma unroll 8
    for (int k = 0; k < 768; k++) acc1h = fmaf(semb[k], fc1w[k * 64 + t], acc1h);
    float sentv = ln64(fmaxf(acc1h, 0.f), lnhg, lnhb, t) + stepsv;
    shh[t] = sentv;
    __builtin_amdgcn_wave_barrier();
    float acc2h = fc2b[t];
    #pragma unroll 8
    for (int k = 0; k < 64; k++) acc2h = fmaf(shh[k], fc2w[k * 64 + t], acc2h);
    __builtin_amdgcn_wave_barrier();
    float sent2 = ln64(fmaxf(acc2h, 0.f), lnhg, lnhb, t);

    float c0 = h2v, c1 = sent2;
    float mu2 = wsum(c0 + c1) * (1.f/128.f);
    float q2  = (c0-mu2)*(c0-mu2) + (c1-mu2)*(c1-mu2);
    float rs2 = rsqrtf(wsum(q2) * (1.f/128.f) + 1e-5f);
    shh[t]      = (c0-mu2)*rs2*lnfg[t]      + lnfb[t];
    shh[64 + t] = (c1-mu2)*rs2*lnfg[64 + t] + lnfb[64 + t];
    __builtin_amdgcn_wave_barrier();

    float acc3h = fc3b[t];
    #pragma unroll 8
    for (int k = 0; k < 128; k++) acc3h = fmaf(shh[k], fc3w[k * 64 + t], acc3h);
    float a2v = ln64(fmaxf(acc3h, 0.f), lnhg, lnhb, t);
    shh[128 + t] = a2v;
    __builtin_amdgcn_wave_barrier();

    float val = wsum(a2v * valw[t]) + valb[0];
    float advv = 0.f;
    if (t < 32){
      advv = advb[t];
      #pragma unroll 8
      for (int k = 0; k < 64; k++) advv = fmaf(shh[128 + k], advw[k * 32 + t], advv);
    }
    float am = wsum(t < 32 ? advv : 0.f) * (1.f/32.f);
    if (t < 32) logits[t] = tanhf(val + advv - am);
  }
}

extern "C" void kernel_launch(void* const* d_in, const int* in_sizes, int n_in,
                              void* d_out, int out_size, void* d_ws, size_t ws_size,
                              hipStream_t stream) {
  const float* x     = (const float*)d_in[0];
  const int*   ei    = (const int*)  d_in[1];
  const float* semb  = (const float*)d_in[2];
  const int*   act   = (const int*)  d_in[3];
  const int*   step  = (const int*)  d_in[4];
  const float* W1    = (const float*)d_in[5];
  const float* as1   = (const float*)d_in[6];
  const float* ad1   = (const float*)d_in[7];
  const float* b1    = (const float*)d_in[8];
  const float* W2    = (const float*)d_in[9];
  const float* as2   = (const float*)d_in[10];
  const float* ad2   = (const float*)d_in[11];
  const float* b2    = (const float*)d_in[12];
  const float* fc0w  = (const float*)d_in[13];
  const float* fc0b  = (const float*)d_in[14];
  const float* fc1w  = (const float*)d_in[15];
  const float* fc1b  = (const float*)d_in[16];
  const float* fc2w  = (const float*)d_in[17];
  const float* fc2b  = (const float*)d_in[18];
  const float* fc3w  = (const float*)d_in[19];
  const float* fc3b  = (const float*)d_in[20];
  const float* valw  = (const float*)d_in[21];
  const float* valb  = (const float*)d_in[22];
  const float* advw  = (const float*)d_in[23];
  const float* advb  = (const float*)d_in[24];
  const float* lnhg  = (const float*)d_in[25];
  const float* lnhb  = (const float*)d_in[26];
  const float* lnfg  = (const float*)d_in[27];
  const float* lnfb  = (const float*)d_in[28];
  const float* lnag  = (const float*)d_in[29];
  const float* lnab  = (const float*)d_in[30];

  char* ws = (char*)d_ws;
  size_t o = 0;
  auto alloc = [&](size_t bytes) -> void* {
    o = (o + 255) & ~(size_t)255;
    void* p = ws + o;
    o += bytes;
    return p;
  };
  int*   deg     = (int*)  alloc((size_t)(NN + 1) * 4);
  int*   off     = (int*)  alloc((size_t)(NN + 1) * 4);
  int*   cur     = (int*)  alloc((size_t)NN * 4);
  int*   bsum    = (int*)  alloc((size_t)(SCAN_NB + 1) * 4);
  int*   csr_src = (int*)  alloc((size_t)ET * 4);
  int*   csr_eid = (int*)  alloc((size_t)ET * 4);
  short* Wp1     = (short*)alloc((size_t)4096 * 8 * 2);   // 64 KB
  short* Wp2     = (short*)alloc((size_t)2048 * 8 * 2);   // 32 KB
  unsigned short* H1b = (unsigned short*)alloc((size_t)NN * 256 * 2);  // bf16 H1
  unsigned short* h1b = (unsigned short*)alloc((size_t)NN * 256 * 2);  // bf16 h1 (post agg1)
  float* es1     = (float*)alloc((size_t)NN * 16);
  float* ed1     = (float*)alloc((size_t)NN * 16);
  unsigned short* H2b = H1b;   // aliases; lifetimes don't overlap
  float* es2 = es1;
  float* ed2 = ed1;

  float* logits    = (float*)d_out;
  float* h2out     = (float*)d_out + 32;
  float* alpha_out = (float*)d_out + 32 + (size_t)NN * 64;

  // CSR build (full-grid kernels; atomics need the parallelism)
  hipMemsetAsync(deg, 0, (size_t)NN * 4, stream);
  degree_kernel<<<(ET + 255) / 256, 256, 0, stream>>>(ei, deg);
  scan_part<<<SCAN_NB, 256, 0, stream>>>(deg, off, bsum, NN);
  scan_top <<<1, 64, 0, stream>>>(bsum, SCAN_NB);
  scan_add <<<SCAN_NB, 256, 0, stream>>>(off, cur, bsum, NN, SCAN_NB);
  fill_csr<<<(ET + 255) / 256, 256, 0, stream>>>(ei, cur, csr_src, csr_eid);
  pack_both<<<24, 256, 0, stream>>>(W1, W2, Wp1, Wp2);

  // layer 1: MFMA GEMM + fused att dots
  mfma_gemm_att<4, 16, 4, true><<<(NN + 63) / 64, 256, 0, stream>>>(
      Wp1, x, nullptr, H1b, as1, ad1, es1, ed1, NN);
  agg1_kernel<<<NN / 4, 256, 0, stream>>>(off, csr_src, H1b, es1, ed1, b1, lnag, lnab, h1b, NN);

  // layer 2
  mfma_gemm_att<8, 4, 1, false><<<(NN + 63) / 64, 256, 0, stream>>>(
      Wp2, nullptr, h1b, H2b, as2, ad2, es2, ed2, NN);
  agg2_head<<<NN / 4, 256, 0, stream>>>(off, csr_src, csr_eid, H2b, es2, ed2, b2,
                                        lnhg, lnhb,
                                        semb, act, step,
                                        fc0w, fc0b, fc1w, fc1b, fc2w, fc2b, fc3w, fc3b,
                                        valw, valb, advw, advb,
                                        lnhg, lnhb, lnfg, lnfb,
                                        h2out, alpha_out, logits, NN);
}